// Round 9
// baseline (4058.597 us; speedup 1.0000x reference)
//
#include <hip/hip_runtime.h>
#include <math.h>

#ifndef M_PI
#define M_PI 3.14159265358979323846
#endif

#define NXx   360
#define NXY   (NXx*NXx)
#define NTRc  32
#define NMEASc 256
#define NSTEPSc 640
#define NBCc  15
#define PADc  73
#define NVc   214

#define BROWS 45
#define NBANDS 8
#define NBLK  (NTRc*NBANDS)     // 256 blocks == 256 CUs
#define NTHREADS 896            // 14 waves: 4 edge, 10 interior
#define NGrow (NXx/4)           // 90
#define LDSROWS 49
#define LDSFLOATS (2*LDSROWS*NXx)
#define NSLOT 4
#define HALO_PER (NSLOT*4*NXx)  // 4 slots x 4 rows x 360

#define C2f   1.3333334f
#define C3f  (-0.083333336f)
#define ADX2  0.11111111f
#define DT2f  0.04f
#define DTf   0.2f
#define DXf   0.6f

typedef float f32x4 __attribute__((ext_vector_type(4)));

// ---- system-coherent (sc0 sc1) transport: executes at chip coherence point,
// bypasses L1/L2 -> no wbl2/inv fences needed (proven R7).
__device__ __forceinline__ void store4_sys(float* p, float4 v) {
    f32x4 vv; vv.x = v.x; vv.y = v.y; vv.z = v.z; vv.w = v.w;
    asm volatile("global_store_dwordx4 %0, %1, off sc0 sc1" :: "v"(p), "v"(vv) : "memory");
}
__device__ __forceinline__ void load4x2_sys(const float* p0, const float* p1,
                                            float4& a, float4& b) {
    f32x4 r0, r1;
    asm volatile("global_load_dwordx4 %0, %2, off sc0 sc1\n\t"
                 "global_load_dwordx4 %1, %3, off sc0 sc1\n\t"
                 "s_waitcnt vmcnt(0)"
                 : "=&v"(r0), "=&v"(r1) : "v"(p0), "v"(p1) : "memory");
    a = make_float4(r0.x, r0.y, r0.z, r0.w);
    b = make_float4(r1.x, r1.y, r1.z, r1.w);
}
__device__ __forceinline__ void storei_sys(int* p, int v) {
    asm volatile("global_store_dword %0, %1, off sc0 sc1" :: "v"(p), "v"(v) : "memory");
}
__device__ __forceinline__ int loadi_sys(const int* p) {
    int r;
    asm volatile("global_load_dword %0, %1, off sc0 sc1\n\ts_waitcnt vmcnt(0)"
                 : "=&v"(r) : "v"(p) : "memory");
    return r;
}
__device__ __forceinline__ void drain_vm() {
    asm volatile("s_waitcnt vmcnt(0)" ::: "memory");
}

__global__ void velmin_kernel(const float* __restrict__ v, float* __restrict__ velmin) {
    __shared__ float s[256];
    float m = 1.5f;
    for (int i = threadIdx.x; i < NVc*NVc; i += 256) m = fminf(m, v[i]);
    s[threadIdx.x] = m;
    __syncthreads();
    for (int o = 128; o > 0; o >>= 1) {
        if (threadIdx.x < o) s[threadIdx.x] = fminf(s[threadIdx.x], s[threadIdx.x+o]);
        __syncthreads();
    }
    if (threadIdx.x == 0) *velmin = s[0];
}

__global__ void coef_kernel(const float* __restrict__ v, const float* __restrict__ velmin_p,
                            float* __restrict__ alpha, float* __restrict__ kap) {
    int idx = blockIdx.x*256 + threadIdx.x;
    if (idx >= NXY) return;
    int i = idx / NXx, j = idx - i*NXx;
    float vc = 1.5f;
    if (i >= PADc && i < PADc+NVc && j >= PADc && j < PADc+NVc)
        vc = v[(i-PADc)*NVc + (j-PADc)];
    float v2 = vc*vc;
    float al = v2 * ADX2;
    float velmin = *velmin_p;
    const float a = (float)((NBCc-1)*0.6);
    float ks = 3.0f*velmin*9.2103405f/(2.0f*a);
    float damp = 0.0f;
    int k = -1;
    if (j >= NXx-NBCc)      k = j-(NXx-NBCc);
    else if (j < NBCc)      k = NBCc-1-j;
    else if (i >= NXx-NBCc) k = i-(NXx-NBCc);
    else if (i < NBCc)      k = NBCc-1-i;
    if (k >= 0) { float r = (float)k*DXf/a; damp = ks*r*r; }
    alpha[idx] = al;
    kap[idx]   = damp*DTf;
}

__global__ void beta_kernel(const float* __restrict__ v, const int* __restrict__ in_inds,
                            float* __restrict__ beta) {
    int tr = threadIdx.x;
    if (tr >= NTRc) return;
    int idx = in_inds[tr];
    int i = idx / NXx, j = idx - i*NXx;
    float vc = 1.5f;
    if (i >= PADc && i < PADc+NVc && j >= PADc && j < PADc+NVc)
        vc = v[(i-PADc)*NVc + (j-PADc)];
    beta[tr] = DT2f*vc*vc;
}

// Persistent LDS-resident kernel; 5-row strips with prev-in-registers;
// barrier-free intra-step schedule (one __syncthreads per step).
//   waves 0-1: strip s0 (rows 0-4, FWD order) -> publish halo rows 0,1 early
//   waves 2-3: strip s8 (rows 40-44, REV order) -> publish rows 43,44 early
//   waves 4-13: strips s1..s7 (interior) + measurement gather
// Edge waves: compute -> drain -> LDS-counter -> [tid64: flag publish] ->
// poll neighbor flag -> pull halos. Interior never blocks on sync.
__global__ __launch_bounds__(NTHREADS, 4) void persist_kernel(
    const float* __restrict__ alpha, const float* __restrict__ kap,
    const float* __restrict__ beta, const float* __restrict__ src,
    const int* __restrict__ meas_inds, const int* __restrict__ in_inds,
    int* flags, float* haloG, float* __restrict__ out)
{
    extern __shared__ float lds[];
    unsigned* cnt = (unsigned*)(lds + LDSFLOATS);
    const int tid  = threadIdx.x;
    const int b    = blockIdx.x;
    const int tr   = b >> 3, band = b & 7;
    const int band0 = band*BROWS;
    const int up = (tr<<3) | ((band+7)&7);
    const int dn = (tr<<3) | ((band+1)&7);

    float* buf0 = lds;
    float* buf1 = lds + LDSROWS*NXx;

    for (int i = tid; i < LDSFLOATS + 4; i += NTHREADS) lds[i] = 0.0f;

    const float betaV = beta[tr];
    const int sCell = in_inds[tr];
    const int sr = sCell/NXx, scc = sCell - sr*NXx;

    // thread -> (strip, jg) mapping; edge strips occupy whole waves
    int sIdx = -1, jg = 0;
    if      (tid < 90)                { sIdx = 0; jg = tid; }            // waves 0-1
    else if (tid >= 128 && tid < 218) { sIdx = 8; jg = tid - 128; }      // waves 2-3
    else if (tid >= 256 && tid < 886) { int idx = tid - 256; sIdx = 1 + idx/90; jg = idx - 90*(idx/90); }
    const bool isStrip = (sIdx >= 0);
    const bool isTop   = (sIdx == 0);
    const bool isEdge  = (sIdx == 0) || (sIdx == 8);
    const int r0 = 5*sIdx;
    const int jgm = (jg==0) ? NGrow-1 : jg-1;
    const int jgp = (jg==NGrow-1) ? 0 : jg+1;

    float4 Ar[5], Kr[5], Pv[5];
    int qrow = -1, qcomp = 0;
    if (isStrip) {
#pragma unroll
        for (int k = 0; k < 5; ++k) {
            int gi = (band0 + r0 + k)*NXx + jg*4;
            Ar[k] = *(const float4*)(alpha + gi);
            Kr[k] = *(const float4*)(kap + gi);
            Pv[k] = make_float4(0.f, 0.f, 0.f, 0.f);
        }
        int sb = sr - band0;
        if (sb >= r0 && sb < r0+5 && (scc>>2) == jg) { qrow = sb - r0; qcomp = scc & 3; }
    } else {
#pragma unroll
        for (int k = 0; k < 5; ++k) { Ar[k] = make_float4(0,0,0,0); Kr[k] = Ar[k]; Pv[k] = Ar[k]; }
    }

    bool mOwn = false; int mOff = 0;
    float* outP = out;
    if (tid >= 256 && tid < 512) {
        int mIdx = tid - 256;
        int mi = meas_inds[mIdx]; int row = mi/NXx, col = mi - row*NXx;
        if (row >= band0 && row < band0+BROWS) {
            mOwn = true; mOff = (row-band0+2)*NXx + col;
            outP = out + ((size_t)tr*NSTEPSc)*NMEASc + mIdx;
        }
    }

    float* myHalo = haloG + (size_t)b*HALO_PER;
    float* upHalo = haloG + (size_t)up*HALO_PER;
    float* dnHalo = haloG + (size_t)dn*HALO_PER;

    __syncthreads();

#define CELL_BODY(KIDX) \
    float4 Lv = cur4[ci - jg + jgm]; \
    float4 Rv = cur4[ci - jg + jgp]; \
    float4 po; \
    { float lap = C2f*(cm1.x+cp1.x+Lv.w+cc0.y) + C3f*(cm2.x+cp2.x+Lv.z+cc0.z); \
      float t1v = 2.0f + 2.0f*(-2.5f)*Ar[KIDX].x - Kr[KIDX].x; float t0v = 1.0f - Kr[KIDX].x; \
      po.x = Ar[KIDX].x*lap + t1v*cc0.x - t0v*Pv[KIDX].x; } \
    { float lap = C2f*(cm1.y+cp1.y+cc0.x+cc0.z) + C3f*(cm2.y+cp2.y+Lv.w+cc0.w); \
      float t1v = 2.0f + 2.0f*(-2.5f)*Ar[KIDX].y - Kr[KIDX].y; float t0v = 1.0f - Kr[KIDX].y; \
      po.y = Ar[KIDX].y*lap + t1v*cc0.y - t0v*Pv[KIDX].y; } \
    { float lap = C2f*(cm1.z+cp1.z+cc0.y+cc0.w) + C3f*(cm2.z+cp2.z+cc0.x+Rv.x); \
      float t1v = 2.0f + 2.0f*(-2.5f)*Ar[KIDX].z - Kr[KIDX].z; float t0v = 1.0f - Kr[KIDX].z; \
      po.z = Ar[KIDX].z*lap + t1v*cc0.z - t0v*Pv[KIDX].z; } \
    { float lap = C2f*(cm1.w+cp1.w+cc0.z+Rv.x) + C3f*(cm2.w+cp2.w+cc0.y+Rv.y); \
      float t1v = 2.0f + 2.0f*(-2.5f)*Ar[KIDX].w - Kr[KIDX].w; float t0v = 1.0f - Kr[KIDX].w; \
      po.w = Ar[KIDX].w*lap + t1v*cc0.w - t0v*Pv[KIDX].w; } \
    if (KIDX == qrow) { float add = betaV*srcT; \
        po.x += (qcomp==0)?add:0.0f; po.y += (qcomp==1)?add:0.0f; \
        po.z += (qcomp==2)?add:0.0f; po.w += (qcomp==3)?add:0.0f; } \
    nxt4[ci] = po; \
    Pv[KIDX] = cc0;

// forward strip (rows low->high); DOHALO publishes rows k=0,1 (top edge)
#define STRIP_FWD(DOHALO) { \
    const int base = r0*NGrow + jg; \
    float4 cm2 = cur4[base]; \
    float4 cm1 = cur4[base+NGrow]; \
    float4 cc0 = cur4[base+2*NGrow]; \
    float4 cp1 = cur4[base+3*NGrow]; \
    float4 cp2 = cur4[base+4*NGrow]; \
    _Pragma("unroll") \
    for (int k = 0; k < 5; ++k) { \
        const int ci = base + (2+k)*NGrow; \
        CELL_BODY(k) \
        if (DOHALO && k < 2) store4_sys(myHalo + hsOff + k*NXx + jg*4, po); \
        cm2 = cm1; cm1 = cc0; cc0 = cp1; cp1 = cp2; \
        if (k < 4) cp2 = cur4[base + (5+k)*NGrow]; \
    } }

// reversed strip (rows high->low); DOHALO publishes rows k=4,3 (bottom edge)
#define STRIP_REV(DOHALO) { \
    const int base = r0*NGrow + jg; \
    float4 cp2 = cur4[base+8*NGrow]; \
    float4 cp1 = cur4[base+7*NGrow]; \
    float4 cc0 = cur4[base+6*NGrow]; \
    float4 cm1 = cur4[base+5*NGrow]; \
    float4 cm2 = cur4[base+4*NGrow]; \
    _Pragma("unroll") \
    for (int kk = 0; kk < 5; ++kk) { \
        const int k = 4 - kk; \
        const int ci = base + (2+k)*NGrow; \
        CELL_BODY(k) \
        if (DOHALO && k >= 3) store4_sys(myHalo + hsOff + (k-1)*NXx + jg*4, po); \
        cp2 = cp1; cp1 = cc0; cc0 = cm1; cm1 = cm2; \
        if (kk < 4) cm2 = cur4[base + (k-1)*NGrow]; \
    } }

    for (int t = 0; t < NSTEPSc; ++t) {
        const int slot = t & 1;
        const int hs   = (t+1) & 3;
        const int hsOff = hs*4*NXx;
        float* cur = (slot == 0) ? buf0 : buf1;
        float* nxt = (slot == 0) ? buf1 : buf0;
        const float4* cur4 = (const float4*)cur;
        float4* nxt4 = (float4*)nxt;
        const float srcT = src[t];

        // measurement gather for field t (from completed cur) — interior waves
        if (mOwn && t > 0) outP[(size_t)(t-1)*NMEASc] = cur[mOff];

        if (isEdge) {
            if (isTop) { STRIP_FWD(true) } else { STRIP_REV(true) }
            drain_vm();   // halo sys-stores acked at coherence point
            if ((tid & 63) == 0) atomicAdd(cnt, 1u);
            if (tid == 64) {   // flag setter: all 4 edge waves drained
                int g = 0;
                while (__hip_atomic_load(cnt, __ATOMIC_RELAXED, __HIP_MEMORY_SCOPE_WORKGROUP)
                       < 4u*(unsigned)(t+1)) { if (++g > 20000000) break; }
                storei_sys(flags + b, t + 1);
            }
            if (tid == 0 || tid == 64) {
                int g = 0;
                while (loadi_sys(flags + up) <= t)
                    { __builtin_amdgcn_s_sleep(1); if (++g > 2000000) break; }
            }
            if (tid == 128 || tid == 192) {
                int g = 0;
                while (loadi_sys(flags + dn) <= t)
                    { __builtin_amdgcn_s_sleep(1); if (++g > 2000000) break; }
            }
            // pull field t+1 halos into nxt rows {0,1} / {47,48}
            float4 ha, hb;
            if (isTop) {
                load4x2_sys(upHalo + hsOff + 2*NXx + jg*4, upHalo + hsOff + 3*NXx + jg*4, ha, hb);
                *(float4*)(nxt + jg*4)       = ha;
                *(float4*)(nxt + NXx + jg*4) = hb;
            } else {
                load4x2_sys(dnHalo + hsOff + jg*4, dnHalo + hsOff + NXx + jg*4, ha, hb);
                *(float4*)(nxt + 47*NXx + jg*4) = ha;
                *(float4*)(nxt + 48*NXx + jg*4) = hb;
            }
        } else if (isStrip) {
            STRIP_FWD(false)
        }

        __syncthreads();   // nxt complete (interior+edges+halos) -> next step
    }

    // final gather: field 640 lives in buf0 (t=639 odd: nxt was buf0)
    if (mOwn) outP[(size_t)(NSTEPSc-1)*NMEASc] = buf0[mOff];
#undef STRIP_FWD
#undef STRIP_REV
#undef CELL_BODY
}

extern "C" void kernel_launch(void* const* d_in, const int* in_sizes, int n_in,
                              void* d_out, int out_size, void* d_ws, size_t ws_size,
                              hipStream_t stream) {
    const float* v = (const float*)d_in[0];
    float* out = (float*)d_out;

    float* haloG  = (float*)d_ws;                       // NBLK*HALO_PER (no memset needed: flag-gated)
    float* alpha  = haloG + (size_t)NBLK*HALO_PER;      // 129600
    float* kap    = alpha + NXY;                        // 129600
    float* beta   = kap + NXY;                          // 32
    float* velmin = beta + NTRc;                        // 1
    float* src_d  = velmin + 1;                         // 640
    int*   meas_d = (int*)(src_d + NSTEPSc);            // 256
    int*   in_d   = meas_d + NMEASc;                    // 32
    int*   flags  = in_d + NTRc;                        // 256

    static int   h_tab[NMEASc + NTRc];
    static float h_src[NSTEPSc];
    {
        const double step = 2.0*M_PI/256.0;
        for (int k = 0; k < NMEASc; ++k) {
            double th = (double)k * step;
            int ti0 = (int)floor(160.0*cos(th) + 179.5);
            int ti1 = (int)floor(160.0*sin(th) + 179.5);
            h_tab[k] = NXx*ti0 + ti1;
        }
        for (int r = 0; r < NTRc; ++r) h_tab[NMEASc + r] = h_tab[r*(NMEASc/NTRc)];
        for (int t = 0; t < NSTEPSc; ++t) {
            double tt = (double)t * 0.2;
            double d  = tt - 3.2;
            double e  = exp(-(d*d) / 288.0);
            double s  = sin(6.283185307179586 * tt);
            h_src[t] = (float)(e * s);
        }
    }
    (void)hipMemcpyAsync(meas_d, h_tab, sizeof(int)*(NMEASc+NTRc), hipMemcpyHostToDevice, stream);
    (void)hipMemcpyAsync(src_d, h_src, sizeof(float)*NSTEPSc, hipMemcpyHostToDevice, stream);
    (void)hipMemsetAsync(flags, 0, sizeof(int)*NBLK, stream);   // flags must start at 0

    velmin_kernel<<<1, 256, 0, stream>>>(v, velmin);
    coef_kernel<<<(NXY+255)/256, 256, 0, stream>>>(v, velmin, alpha, kap);
    beta_kernel<<<1, 64, 0, stream>>>(v, in_d, beta);

    (void)hipFuncSetAttribute((const void*)persist_kernel,
                        hipFuncAttributeMaxDynamicSharedMemorySize, (LDSFLOATS+4)*4);

    persist_kernel<<<NBLK, NTHREADS, (LDSFLOATS+4)*4, stream>>>(
        alpha, kap, beta, src_d, meas_d, in_d, flags, haloG, out);
}

// Round 10
// 2826.376 us; speedup vs baseline: 1.4360x; 1.4360x over previous
//
#include <hip/hip_runtime.h>
#include <math.h>

#ifndef M_PI
#define M_PI 3.14159265358979323846
#endif

#define NXx   360
#define NXY   (NXx*NXx)
#define NTRc  32
#define NMEASc 256
#define NSTEPSc 640
#define NBCc  15
#define PADc  73
#define NVc   214

#define BROWS 45
#define NBANDS 8
#define NBLK  (NTRc*NBANDS)     // 256 blocks == 256 CUs
#define NTHREADS 1024
#define NG    (NXx/4)           // 90 groups/row
#define LDSROWS 49
#define LDSFLOATS (2*LDSROWS*NXx)
#define NSLOT 4
#define HALO_PER (NSLOT*4*NXx)  // 4 slots x 4 rows x 360

#define C2f   1.3333334f
#define C3f  (-0.083333336f)
#define ADX2  0.11111111f
#define DT2f  0.04f
#define DTf   0.2f
#define DXf   0.6f

typedef float f32x4 __attribute__((ext_vector_type(4)));

// ---- system-coherent (sc0 sc1) transport (proven R7): coherence-point ops,
// no wbl2/inv fences needed.
__device__ __forceinline__ void store4_sys(float* p, float4 v) {
    f32x4 vv; vv.x = v.x; vv.y = v.y; vv.z = v.z; vv.w = v.w;
    asm volatile("global_store_dwordx4 %0, %1, off sc0 sc1" :: "v"(p), "v"(vv) : "memory");
}
__device__ __forceinline__ float4 load4_sys(const float* p) {
    f32x4 r;
    asm volatile("global_load_dwordx4 %0, %1, off sc0 sc1\n\ts_waitcnt vmcnt(0)"
                 : "=&v"(r) : "v"(p) : "memory");
    return make_float4(r.x, r.y, r.z, r.w);
}
__device__ __forceinline__ void storei_sys(int* p, int v) {
    asm volatile("global_store_dword %0, %1, off sc0 sc1" :: "v"(p), "v"(v) : "memory");
}
__device__ __forceinline__ int loadi_sys(const int* p) {
    int r;
    asm volatile("global_load_dword %0, %1, off sc0 sc1\n\ts_waitcnt vmcnt(0)"
                 : "=&v"(r) : "v"(p) : "memory");
    return r;
}
__device__ __forceinline__ void drain_vm() {
    asm volatile("s_waitcnt vmcnt(0)" ::: "memory");
}

__global__ void velmin_kernel(const float* __restrict__ v, float* __restrict__ velmin) {
    __shared__ float s[256];
    float m = 1.5f;
    for (int i = threadIdx.x; i < NVc*NVc; i += 256) m = fminf(m, v[i]);
    s[threadIdx.x] = m;
    __syncthreads();
    for (int o = 128; o > 0; o >>= 1) {
        if (threadIdx.x < o) s[threadIdx.x] = fminf(s[threadIdx.x], s[threadIdx.x+o]);
        __syncthreads();
    }
    if (threadIdx.x == 0) *velmin = s[0];
}

__global__ void coef_kernel(const float* __restrict__ v, const float* __restrict__ velmin_p,
                            float* __restrict__ alpha, float* __restrict__ kap) {
    int idx = blockIdx.x*256 + threadIdx.x;
    if (idx >= NXY) return;
    int i = idx / NXx, j = idx - i*NXx;
    float vc = 1.5f;
    if (i >= PADc && i < PADc+NVc && j >= PADc && j < PADc+NVc)
        vc = v[(i-PADc)*NVc + (j-PADc)];
    float v2 = vc*vc;
    float al = v2 * ADX2;
    float velmin = *velmin_p;
    const float a = (float)((NBCc-1)*0.6);
    float ks = 3.0f*velmin*9.2103405f/(2.0f*a);
    float damp = 0.0f;
    int k = -1;
    if (j >= NXx-NBCc)      k = j-(NXx-NBCc);
    else if (j < NBCc)      k = NBCc-1-j;
    else if (i >= NXx-NBCc) k = i-(NXx-NBCc);
    else if (i < NBCc)      k = NBCc-1-i;
    if (k >= 0) { float r = (float)k*DXf/a; damp = ks*r*r; }
    alpha[idx] = al;
    kap[idx]   = damp*DTf;
}

__global__ void beta_kernel(const float* __restrict__ v, const int* __restrict__ in_inds,
                            float* __restrict__ beta) {
    int tr = threadIdx.x;
    if (tr >= NTRc) return;
    int idx = in_inds[tr];
    int i = idx / NXx, j = idx - i*NXx;
    float vc = 1.5f;
    if (i >= PADc && i < PADc+NVc && j >= PADc && j < PADc+NVc)
        vc = v[(i-PADc)*NVc + (j-PADc)];
    beta[tr] = DT2f*vc*vc;
}

// R7 schedule + interior 5-row strips + wave-specialized concurrent pulls.
//  phase 1 (tid<360): edge rows 0,1,43,44 (1 group/thread) -> nxt + halo
//                     publish (sc0sc1) -> drain.  [thin, proven R7 form]
//  barrier; tid0 publishes flag (halos already at coherence point).
//  phase 2 (concurrent):
//    tid<720   : 5-row strips, rows 2..41; alpha/kap streamed from global
//                (VMEM pipe), p0 read in-place from nxt. 29 LDS b128/strip.
//    720..809  : row 42, flat.
//    wave 13   : poll up flag -> pull 2 up-halo rows into nxt rows 0,1
//    wave 14   : poll dn flag -> pull 2 dn-halo rows into nxt rows 47,48
//  barrier. Gather for field t at top of step t+1 (reads settled cur).
__global__ __launch_bounds__(NTHREADS, 4) void persist_kernel(
    const float* __restrict__ alpha, const float* __restrict__ kap,
    const float* __restrict__ beta, const float* __restrict__ src,
    const int* __restrict__ meas_inds, const int* __restrict__ in_inds,
    int* flags, float* haloG, float* __restrict__ out)
{
    extern __shared__ float lds[];
    const int tid  = threadIdx.x;
    const int b    = blockIdx.x;
    const int tr   = b >> 3, band = b & 7;
    const int band0 = band*BROWS;
    const int up = (tr<<3) | ((band+7)&7);
    const int dn = (tr<<3) | ((band+1)&7);

    float* buf0 = lds;
    float* buf1 = lds + LDSROWS*NXx;

    for (int i = tid; i < LDSFLOATS; i += NTHREADS) lds[i] = 0.0f;

    const float betaV = beta[tr];
    const int sCell = in_inds[tr];
    const int sr = sCell/NXx, scc = sCell - sr*NXx;
    const int sb = sr - band0;          // source row within band (may be outside)
    const int sq = scc >> 2, sqc = scc & 3;

    // ---- edge role (tid < 360): one group, rows {0,1,43,44} ----
    const bool isEdgeT = (tid < 360);
    int eCi = 0, eL = 0, eR = 0, eH = 0, eQ = -1;
    float4 eA = make_float4(0,0,0,0), eK = eA;
    if (isEdgeT) {
        int kk = tid/NG, jg = tid - kk*NG;
        int rowG = (kk < 2) ? kk : (41 + kk);          // 0,1,43,44
        int ldsR = rowG + 2;                           // 2,3,45,46
        eCi = ldsR*NG + jg;
        eL  = eCi - jg + ((jg==0) ? NG-1 : jg-1);
        eR  = eCi - jg + ((jg==NG-1) ? 0 : jg+1);
        eH  = kk*NXx + jg*4;
        int gi = (band0 + rowG)*NXx + jg*4;
        eA = *(const float4*)(alpha + gi);
        eK = *(const float4*)(kap + gi);
        eQ = (sb == rowG && sq == jg) ? sqc : -1;
    }

    // ---- strip role (tid < 720): rows 2+5s .. 6+5s ----
    const bool isStripT = (tid < 720);
    int sBase = 0, sLo = 0, sRo = 0, sQk = -1;
    const float* aP = alpha; const float* kP = kap;
    if (isStripT) {
        int ss = tid/NG, jg = tid - ss*NG;
        sBase = (4 + 5*ss)*NG + jg;
        sLo = (jg==0) ? NG-1 : -1;
        sRo = (jg==NG-1) ? -(NG-1) : 1;
        aP = alpha + (band0 + 2 + 5*ss)*NXx + jg*4;
        kP = kap   + (band0 + 2 + 5*ss)*NXx + jg*4;
        sQk = (sb >= 2+5*ss && sb < 7+5*ss && sq == jg) ? (sb - 2 - 5*ss) : -1;
    }

    // ---- flat row 42 (720 <= tid < 810) ----
    const bool isFlatT = (tid >= 720 && tid < 810);
    int fCi = 0, fL = 0, fR = 0, fQ = -1;
    const float* aPf = alpha; const float* kPf = kap;
    if (isFlatT) {
        int jg = tid - 720;
        fCi = 44*NG + jg;
        fL  = fCi - jg + ((jg==0) ? NG-1 : jg-1);
        fR  = fCi - jg + ((jg==NG-1) ? 0 : jg+1);
        aPf = alpha + (band0 + 42)*NXx + jg*4;
        kPf = kap   + (band0 + 42)*NXx + jg*4;
        fQ = (sb == 42 && sq == jg) ? sqc : -1;
    }

    // ---- measurement role (tid < 256) ----
    bool mOwn = false; int mOff = 0;
    float* outP = out;
    if (tid < NMEASc) {
        int mi = meas_inds[tid]; int row = mi/NXx, col = mi - row*NXx;
        if (row >= band0 && row < band0+BROWS) {
            mOwn = true; mOff = (row-band0+2)*NXx + col;
            outP = out + ((size_t)tr*NSTEPSc)*NMEASc + tid;
        }
    }

    float* myHalo = haloG + (size_t)b*HALO_PER;
    float* upHalo = haloG + (size_t)up*HALO_PER;
    float* dnHalo = haloG + (size_t)dn*HALO_PER;

    __syncthreads();

#define CELLMATH(Cv,U1,D1,U2,D2,Lv,Rv,Pp,AA,KK,QQ) \
    float4 po; \
    { float lap = C2f*(U1.x+D1.x+Lv.w+Cv.y) + C3f*(U2.x+D2.x+Lv.z+Cv.z); \
      float t1v = 2.0f + 2.0f*(-2.5f)*AA.x - KK.x; float t0v = 1.0f - KK.x; \
      po.x = AA.x*lap + t1v*Cv.x - t0v*Pp.x; } \
    { float lap = C2f*(U1.y+D1.y+Cv.x+Cv.z) + C3f*(U2.y+D2.y+Lv.w+Cv.w); \
      float t1v = 2.0f + 2.0f*(-2.5f)*AA.y - KK.y; float t0v = 1.0f - KK.y; \
      po.y = AA.y*lap + t1v*Cv.y - t0v*Pp.y; } \
    { float lap = C2f*(U1.z+D1.z+Cv.y+Cv.w) + C3f*(U2.z+D2.z+Cv.x+Rv.x); \
      float t1v = 2.0f + 2.0f*(-2.5f)*AA.z - KK.z; float t0v = 1.0f - KK.z; \
      po.z = AA.z*lap + t1v*Cv.z - t0v*Pp.z; } \
    { float lap = C2f*(U1.w+D1.w+Cv.z+Rv.x) + C3f*(U2.w+D2.w+Cv.y+Rv.y); \
      float t1v = 2.0f + 2.0f*(-2.5f)*AA.w - KK.w; float t0v = 1.0f - KK.w; \
      po.w = AA.w*lap + t1v*Cv.w - t0v*Pp.w; } \
    if (QQ >= 0) { float add = betaV*srcT; \
        po.x += (QQ==0)?add:0.0f; po.y += (QQ==1)?add:0.0f; \
        po.z += (QQ==2)?add:0.0f; po.w += (QQ==3)?add:0.0f; }

    for (int t = 0; t < NSTEPSc; ++t) {
        const int slot = t & 1;
        const int hsOff = ((t+1) & 3)*4*NXx;
        float* cur = (slot == 0) ? buf0 : buf1;
        float* nxt = (slot == 0) ? buf1 : buf0;
        const float4* cur4 = (const float4*)cur;
        float4* nxt4 = (float4*)nxt;
        const float srcT = src[t];

        // gather for field t (settled in cur after previous barrier)
        if (mOwn && t > 0) outP[(size_t)(t-1)*NMEASc] = cur[mOff];

        // ---- phase 1: thin edge rows + halo publish ----
        if (isEdgeT) {
            float4 Cv = cur4[eCi], Lv = cur4[eL], Rv = cur4[eR];
            float4 U1 = cur4[eCi-NG], D1 = cur4[eCi+NG];
            float4 U2 = cur4[eCi-2*NG], D2 = cur4[eCi+2*NG];
            float4 Pp = nxt4[eCi];
            CELLMATH(Cv,U1,D1,U2,D2,Lv,Rv,Pp,eA,eK,eQ)
            nxt4[eCi] = po;
            store4_sys(myHalo + hsOff + eH, po);
            drain_vm();          // halo stores at coherence point before barrier
        }
        __syncthreads();
        if (tid == 0) storei_sys(flags + b, t + 1);

        // ---- phase 2: strips  ||  flat row 42  ||  poll+pull waves ----
        if (isStripT) {
            int ci = sBase;
            float4 cm2 = cur4[ci-2*NG], cm1 = cur4[ci-NG], cc0 = cur4[ci];
            float4 cp1 = cur4[ci+NG],  cp2 = cur4[ci+2*NG];
#pragma unroll
            for (int k = 0; k < 5; ++k) {
                float4 Al = *(const float4*)(aP + k*NXx);
                float4 Kp = *(const float4*)(kP + k*NXx);
                float4 Lv = cur4[ci + sLo], Rv = cur4[ci + sRo];
                float4 Pp = nxt4[ci];
                CELLMATH(cc0,cm1,cp1,cm2,cp2,Lv,Rv,Pp,Al,Kp,(k==sQk?sqc:-1))
                nxt4[ci] = po;
                cm2 = cm1; cm1 = cc0; cc0 = cp1; cp1 = cp2;
                if (k < 4) cp2 = cur4[ci + 3*NG];
                ci += NG;
            }
        } else if (isFlatT) {
            float4 Al = *(const float4*)(aPf);
            float4 Kp = *(const float4*)(kPf);
            float4 Cv = cur4[fCi], Lv = cur4[fL], Rv = cur4[fR];
            float4 U1 = cur4[fCi-NG], D1 = cur4[fCi+NG];
            float4 U2 = cur4[fCi-2*NG], D2 = cur4[fCi+2*NG];
            float4 Pp = nxt4[fCi];
            CELLMATH(Cv,U1,D1,U2,D2,Lv,Rv,Pp,Al,Kp,fQ)
            nxt4[fCi] = po;
        } else if (tid >= 832 && tid < 896) {
            // wave 13: up halo -> nxt rows 0,1
            if (tid == 832) {
                int g = 0;
                while (loadi_sys(flags + up) <= t)
                    { __builtin_amdgcn_s_sleep(1); if (++g > 2000000) break; }
            }
            int lane = tid - 832;
            for (int i = lane; i < 2*NG; i += 64) {
                int rr = (i < NG) ? 0 : 1, jq = i - rr*NG;
                float4 hv = load4_sys(upHalo + hsOff + (2+rr)*NXx + jq*4);
                *(float4*)(nxt + rr*NXx + jq*4) = hv;
            }
        } else if (tid >= 896 && tid < 960) {
            // wave 14: dn halo -> nxt rows 47,48
            if (tid == 896) {
                int g = 0;
                while (loadi_sys(flags + dn) <= t)
                    { __builtin_amdgcn_s_sleep(1); if (++g > 2000000) break; }
            }
            int lane = tid - 896;
            for (int i = lane; i < 2*NG; i += 64) {
                int rr = (i < NG) ? 0 : 1, jq = i - rr*NG;
                float4 hv = load4_sys(dnHalo + hsOff + rr*NXx + jq*4);
                *(float4*)(nxt + (47+rr)*NXx + jq*4) = hv;
            }
        }

        __syncthreads();
    }
    // final gather: field 640 is in buf0 (t=639: slot=1 -> nxt=buf0)
    if (mOwn) outP[(size_t)(NSTEPSc-1)*NMEASc] = buf0[mOff];
#undef CELLMATH
}

extern "C" void kernel_launch(void* const* d_in, const int* in_sizes, int n_in,
                              void* d_out, int out_size, void* d_ws, size_t ws_size,
                              hipStream_t stream) {
    const float* v = (const float*)d_in[0];
    float* out = (float*)d_out;

    float* haloG  = (float*)d_ws;                       // NBLK*HALO_PER (16B-aligned)
    float* alpha  = haloG + (size_t)NBLK*HALO_PER;      // 129600
    float* kap    = alpha + NXY;                        // 129600
    float* beta   = kap + NXY;                          // 32
    float* velmin = beta + NTRc;                        // 1
    float* src_d  = velmin + 1;                         // 640
    int*   meas_d = (int*)(src_d + NSTEPSc);            // 256
    int*   in_d   = meas_d + NMEASc;                    // 32
    int*   flags  = in_d + NTRc;                        // 256

    static int   h_tab[NMEASc + NTRc];
    static float h_src[NSTEPSc];
    {
        const double step = 2.0*M_PI/256.0;
        for (int k = 0; k < NMEASc; ++k) {
            double th = (double)k * step;
            int ti0 = (int)floor(160.0*cos(th) + 179.5);
            int ti1 = (int)floor(160.0*sin(th) + 179.5);
            h_tab[k] = NXx*ti0 + ti1;
        }
        for (int r = 0; r < NTRc; ++r) h_tab[NMEASc + r] = h_tab[r*(NMEASc/NTRc)];
        for (int t = 0; t < NSTEPSc; ++t) {
            double tt = (double)t * 0.2;
            double d  = tt - 3.2;
            double e  = exp(-(d*d) / 288.0);
            double s  = sin(6.283185307179586 * tt);
            h_src[t] = (float)(e * s);
        }
    }
    (void)hipMemcpyAsync(meas_d, h_tab, sizeof(int)*(NMEASc+NTRc), hipMemcpyHostToDevice, stream);
    (void)hipMemcpyAsync(src_d, h_src, sizeof(float)*NSTEPSc, hipMemcpyHostToDevice, stream);
    (void)hipMemsetAsync(haloG, 0, sizeof(float)*(size_t)NBLK*HALO_PER, stream);
    (void)hipMemsetAsync(flags, 0, sizeof(int)*NBLK, stream);

    velmin_kernel<<<1, 256, 0, stream>>>(v, velmin);
    coef_kernel<<<(NXY+255)/256, 256, 0, stream>>>(v, velmin, alpha, kap);
    beta_kernel<<<1, 64, 0, stream>>>(v, in_d, beta);

    (void)hipFuncSetAttribute((const void*)persist_kernel,
                        hipFuncAttributeMaxDynamicSharedMemorySize, LDSFLOATS*4);

    persist_kernel<<<NBLK, NTHREADS, LDSFLOATS*4, stream>>>(
        alpha, kap, beta, src_d, meas_d, in_d, flags, haloG, out);
}